// Round 6
// baseline (236.083 us; speedup 1.0000x reference)
//
#include <hip/hip_runtime.h>
#include <stdint.h>

// Problem: B=8, L=2048, D=512, H=8, P=4, C=64.  M = B*L = 16384.
#define PSZF (16384 * 96)   // elements per offaw partial buffer (split-K half)

using short8  = __attribute__((ext_vector_type(8))) short;
using floatx4 = __attribute__((ext_vector_type(4))) float;

__device__ __forceinline__ unsigned short f2bf(float f) {  // RNE
  union { float f; unsigned u; } v; v.f = f;
  unsigned r = v.u + 0x7fffu + ((v.u >> 16) & 1u);
  return (unsigned short)(r >> 16);
}
__device__ __forceinline__ float bf2f(unsigned short u) {
  union { unsigned u; float f; } v; v.u = ((unsigned)u) << 16; return v.f;
}

__device__ __forceinline__ void load_lds16(const void* g, void* l) {
  __builtin_amdgcn_global_load_lds(
      (const __attribute__((address_space(1))) unsigned int*)g,
      (__attribute__((address_space(3))) unsigned int*)l, 16, 0, 0);
}

__device__ __forceinline__ short8 cvt8(float4 a, float4 b) {
  short8 r;
  r[0] = (short)f2bf(a.x); r[1] = (short)f2bf(a.y);
  r[2] = (short)f2bf(a.z); r[3] = (short)f2bf(a.w);
  r[4] = (short)f2bf(b.x); r[5] = (short)f2bf(b.y);
  r[6] = (short)f2bf(b.z); r[7] = (short)f2bf(b.w);
  return r;
}

// ---------------- K0: weight prep only (value conversion fused into K1) -----------
__global__ __launch_bounds__(256) void prep_all(const float* __restrict__ W_v,
                                                const float* __restrict__ W_out,
                                                const float* __restrict__ Woff,
                                                const float* __restrict__ Waw,
                                                unsigned short* __restrict__ Wv_t,
                                                unsigned short* __restrict__ Wo_t,
                                                unsigned short* __restrict__ Bhi,
                                                unsigned short* __restrict__ Blo) {
  int t = blockIdx.x * 256 + threadIdx.x;
  if (t < 262144) {
    int n = t >> 9, k = t & 511;
    Wv_t[t] = f2bf(W_v[(k << 9) + n]);
    return;
  }
  t -= 262144;
  if (t < 262144) {
    int n = t >> 9, k = t & 511;
    Wo_t[t] = f2bf(W_out[(k << 9) + n]);
    return;
  }
  t -= 262144;
  if (t < 49152) {
    int n = t >> 9, k = t & 511;
    float w = (n < 64) ? Woff[(k << 6) + n] : Waw[(k << 5) + (n - 64)];
    unsigned short hi = f2bf(w);
    Bhi[t] = hi;
    Blo[t] = f2bf(w - bf2f(hi));
  }
}

// ---------------- barrier-free register GEMM, fp32 A (K1: v = value @ Wv^T) -------
// B (Wv_t, 0.5 MB) is L2-resident: fragments load per-wave straight from global.
// A fp32 fragments load straight from global + in-register RNE cvt.  Each wave
// owns a 64x64 output tile; NO LDS, NO barriers -> no convoy stall.  Fragment
// loads are 128B-line coalesced (4 lanes per line).  MFMA k-order and all
// rounding points identical to the LDS path -> bit-identical output.
__device__ __forceinline__ void gemm_reg_f32A(const float* __restrict__ Af,
                                              const unsigned short* __restrict__ Bt,
                                              const float* __restrict__ bias,
                                              unsigned short* __restrict__ C,
                                              int bx, int by) {
  int tid = threadIdx.x;
  int lane = tid & 63, wv = tid >> 6;
  int wm = wv & 1, wn = wv >> 1;
  int lrow = lane & 15, quad = lane >> 4;
  int row0 = by * 128 + wm * 64;        // wave's 64-row strip
  int col0 = bx * 128 + wn * 64;        // wave's 64-col strip

  const float* Ab = Af + (size_t)(row0 + lrow) * 512 + quad * 8;
  const unsigned short* Bb = Bt + (size_t)(col0 + lrow) * 512 + quad * 8;

  floatx4 acc[4][4];
#pragma unroll
  for (int i = 0; i < 4; i++)
#pragma unroll
    for (int j = 0; j < 4; j++) acc[i][j] = (floatx4){0.f, 0.f, 0.f, 0.f};

#pragma unroll 2
  for (int k0 = 0; k0 < 512; k0 += 32) {
    short8 a[4], b[4];
#pragma unroll
    for (int mi = 0; mi < 4; mi++) {
      const float* ap = Ab + (size_t)mi * 16 * 512 + k0;
      float4 lo = *(const float4*)(ap);
      float4 hi = *(const float4*)(ap + 4);
      a[mi] = cvt8(lo, hi);
    }
#pragma unroll
    for (int ni = 0; ni < 4; ni++)
      b[ni] = *(const short8*)(Bb + (size_t)ni * 16 * 512 + k0);
#pragma unroll
    for (int mi = 0; mi < 4; mi++)
#pragma unroll
      for (int ni = 0; ni < 4; ni++)
        acc[mi][ni] = __builtin_amdgcn_mfma_f32_16x16x32_bf16(a[mi], b[ni], acc[mi][ni], 0, 0, 0);
  }

  // C/D layout: col = lane&15, row = quad*4 + reg   [verified m89/m91]
#pragma unroll
  for (int ni = 0; ni < 4; ni++) {
    int col = col0 + ni * 16 + lrow;
    float bv = bias[col];
#pragma unroll
    for (int mi = 0; mi < 4; mi++) {
      int row = row0 + mi * 16 + quad * 4;
#pragma unroll
      for (int r = 0; r < 4; r++)
        C[(size_t)(row + r) * 512 + col] = f2bf(acc[mi][ni][r] + bv);
    }
  }
}

// ---------------- barrier-free register GEMM, bf16 A (K3: out = attn @ Wo^T) ------
__device__ __forceinline__ void gemm_reg_bf16A(const unsigned short* __restrict__ A,
                                               const unsigned short* __restrict__ Bt,
                                               const float* __restrict__ bias,
                                               float* __restrict__ C,
                                               int bx, int by) {
  int tid = threadIdx.x;
  int lane = tid & 63, wv = tid >> 6;
  int wm = wv & 1, wn = wv >> 1;
  int lrow = lane & 15, quad = lane >> 4;
  int row0 = by * 128 + wm * 64;
  int col0 = bx * 128 + wn * 64;

  const unsigned short* Ab = A + (size_t)(row0 + lrow) * 512 + quad * 8;
  const unsigned short* Bb = Bt + (size_t)(col0 + lrow) * 512 + quad * 8;

  floatx4 acc[4][4];
#pragma unroll
  for (int i = 0; i < 4; i++)
#pragma unroll
    for (int j = 0; j < 4; j++) acc[i][j] = (floatx4){0.f, 0.f, 0.f, 0.f};

#pragma unroll 4
  for (int k0 = 0; k0 < 512; k0 += 32) {
    short8 a[4], b[4];
#pragma unroll
    for (int mi = 0; mi < 4; mi++)
      a[mi] = *(const short8*)(Ab + (size_t)mi * 16 * 512 + k0);
#pragma unroll
    for (int ni = 0; ni < 4; ni++)
      b[ni] = *(const short8*)(Bb + (size_t)ni * 16 * 512 + k0);
#pragma unroll
    for (int mi = 0; mi < 4; mi++)
#pragma unroll
      for (int ni = 0; ni < 4; ni++)
        acc[mi][ni] = __builtin_amdgcn_mfma_f32_16x16x32_bf16(a[mi], b[ni], acc[mi][ni], 0, 0, 0);
  }

#pragma unroll
  for (int ni = 0; ni < 4; ni++) {
    int col = col0 + ni * 16 + lrow;
    float bv = bias[col];
#pragma unroll
    for (int mi = 0; mi < 4; mi++) {
      int row = row0 + mi * 16 + quad * 4;
#pragma unroll
      for (int r = 0; r < 4; r++)
        C[(size_t)(row + r) * 512 + col] = acc[mi][ni][r] + bv;
    }
  }
}

// XCD-aware swizzle for 512-block GEMMs.
__device__ __forceinline__ void swz512(int bid, int& bx, int& by) {
  int x = bid & 7, s = bid >> 3;
  by = (x << 4) | (s >> 2);
  bx = s & 3;
}

// ---------------- offaw body: split-bf16 + T14 Q-prefetch + counted vmcnt (R5) ----
__device__ __forceinline__ void offaw_body(unsigned char* smem,
                                           const float* __restrict__ Q,
                                           const unsigned short* __restrict__ Bhi,
                                           const unsigned short* __restrict__ Blo,
                                           const float* __restrict__ boff,
                                           const float* __restrict__ baw,
                                           float* __restrict__ P, int bid) {
  unsigned short* lAhi = (unsigned short*)smem;            // 64*32 = 4 KB
  unsigned short* lAlo = (unsigned short*)(smem + 4096);   // 4 KB
  unsigned short* lBhi = (unsigned short*)(smem + 8192);   // 96*32 = 6 KB
  unsigned short* lBlo = (unsigned short*)(smem + 14336);  // 6 KB (ends at 20480)
  int khalf = bid >> 8, row0 = (bid & 255) * 64, kbase = khalf << 8;
  int tid = threadIdx.x, lane = tid & 63, wv = tid >> 6;
  int wm = wv & 1, wn = wv >> 1, lrow = lane & 15, quad = lane >> 4;

  int ar = tid >> 2, ac = (tid & 3) << 3;
  const float* qp = Q + (size_t)(row0 + ar) * 512 + kbase + ac;

  floatx4 acc[2][3];
#pragma unroll
  for (int i = 0; i < 2; i++)
#pragma unroll
    for (int j = 0; j < 3; j++) acc[i][j] = (floatx4){0.f, 0.f, 0.f, 0.f};

  // prologue: issue Q(k0=0)
  float4 v0 = *(const float4*)(qp);
  float4 v1 = *(const float4*)(qp + 4);

  for (int k0 = 0; k0 < 256; k0 += 32) {
    // B stage first (3 gload_lds, wave-uniform routing)
#pragma unroll
    for (int j = 0; j < 3; j++) {
      int widx = wv + (j << 2);                        // 0..11, wave-uniform
      const unsigned short* src = (widx < 6) ? Bhi : Blo;
      unsigned short* dst = (widx < 6) ? lBhi : lBlo;
      int c = (((widx < 6) ? widx : widx - 6) << 6) + lane;  // 0..383
      int n = c >> 2, cc = (c & 3) << 3;
      load_lds16(src + (size_t)n * 512 + kbase + k0 + cc, dst + c * 8);
    }
    // split-bf16 cvt of Q(k0) from prefetched regs
    {
      float vv[8] = {v0.x, v0.y, v0.z, v0.w, v1.x, v1.y, v1.z, v1.w};
      short8 h8, l8;
#pragma unroll
      for (int e = 0; e < 8; e++) {
        union { float f; unsigned u; } t; t.f = vv[e];
        unsigned r = t.u + 0x7fffu + ((t.u >> 16) & 1u);
        h8[e] = (short)(r >> 16);
        union { unsigned u; float f; } hf; hf.u = r & 0xffff0000u;
        union { float f; unsigned u; } rb; rb.f = vv[e] - hf.f;
        l8[e] = (short)(rb.u >> 16);
      }
      *(short8*)&lAhi[tid * 8] = h8;
      *(short8*)&lAlo[tid * 8] = l8;
    }
    if (k0 < 224) {
      v0 = *(const float4*)(qp + k0 + 32);
      v1 = *(const float4*)(qp + k0 + 36);
      asm volatile("s_waitcnt vmcnt(2)" ::: "memory");   // drain B3; keep Q(next) 2
    } else {
      asm volatile("s_waitcnt vmcnt(0)" ::: "memory");
    }
    asm volatile("s_waitcnt lgkmcnt(0)" ::: "memory");
    __builtin_amdgcn_sched_barrier(0);
    __builtin_amdgcn_s_barrier();
    __builtin_amdgcn_sched_barrier(0);

    short8 ah[2], al[2], bh[3], bl[3];
#pragma unroll
    for (int mi = 0; mi < 2; mi++) {
      int r = (wm * 32 + mi * 16 + lrow) * 32 + quad * 8;
      ah[mi] = *(const short8*)&lAhi[r];
      al[mi] = *(const short8*)&lAlo[r];
    }
#pragma unroll
    for (int ni = 0; ni < 3; ni++) {
      int r = (wn * 48 + ni * 16 + lrow) * 32 + quad * 8;
      bh[ni] = *(const short8*)&lBhi[r];
      bl[ni] = *(const short8*)&lBlo[r];
    }
#pragma unroll
    for (int mi = 0; mi < 2; mi++)
#pragma unroll
      for (int ni = 0; ni < 3; ni++) {
        acc[mi][ni] = __builtin_amdgcn_mfma_f32_16x16x32_bf16(ah[mi], bh[ni], acc[mi][ni], 0, 0, 0);
        acc[mi][ni] = __builtin_amdgcn_mfma_f32_16x16x32_bf16(ah[mi], bl[ni], acc[mi][ni], 0, 0, 0);
        acc[mi][ni] = __builtin_amdgcn_mfma_f32_16x16x32_bf16(al[mi], bh[ni], acc[mi][ni], 0, 0, 0);
      }
    __builtin_amdgcn_sched_barrier(0);
    __builtin_amdgcn_s_barrier();
  }

  float* out = P + (size_t)khalf * PSZF;
#pragma unroll
  for (int ni = 0; ni < 3; ni++) {
    int col = wn * 48 + ni * 16 + lrow;
    float bv = (khalf == 0) ? ((col < 64) ? boff[col] : baw[col - 64]) : 0.0f;
#pragma unroll
    for (int mi = 0; mi < 2; mi++) {
      int row = row0 + wm * 32 + mi * 16 + quad * 4;
#pragma unroll
      for (int r = 0; r < 4; r++)
        out[(size_t)(row + r) * 96 + col] = acc[mi][ni][r] + bv;
    }
  }
}

// ---------------- K1: gemm1 (512 blocks, reg-GEMM) + offaw (512 blocks) -----------
__global__ __launch_bounds__(256) void mega_k1(const float* __restrict__ value,
                                               const unsigned short* __restrict__ Wv_t,
                                               const float* __restrict__ b_v,
                                               unsigned short* __restrict__ v_bf,
                                               const float* __restrict__ query,
                                               const unsigned short* __restrict__ Bhi,
                                               const unsigned short* __restrict__ Blo,
                                               const float* __restrict__ boff,
                                               const float* __restrict__ baw,
                                               float* __restrict__ offP) {
  __shared__ __align__(16) unsigned char smem[20480];   // offaw branch only
  int bid = blockIdx.x;
  if (bid < 512) {
    int bx, by; swz512(bid, bx, by);
    gemm_reg_f32A(value, Wv_t, b_v, v_bf, bx, by);
  } else {
    offaw_body(smem, query, Bhi, Blo, boff, baw, offP, bid - 512);
  }
}

// ---------------- K3: out = attn @ W_out + b_out (512 blocks, reg-GEMM) -----------
__global__ __launch_bounds__(256) void gemm2_k(const unsigned short* __restrict__ A,
                                               const unsigned short* __restrict__ Bt,
                                               const float* __restrict__ bias,
                                               float* __restrict__ C) {
  int bx, by; swz512(blockIdx.x, bx, by);
  gemm_reg_bf16A(A, Bt, bias, C, bx, by);
}

// ---------------- K2: fused softmax + 1-D grid-sample gather ----------------------
__global__ __launch_bounds__(256) void sample_kernel(const float* __restrict__ P,
                                                     const unsigned short* __restrict__ v,
                                                     unsigned short* __restrict__ attn) {
  int tid = threadIdx.x;
  int rr = tid >> 5, hp = tid & 31;
  int row = blockIdx.x * 8 + rr;
  int l = row & 2047;
  __shared__ float s_w0[8][32], s_w1[8][32];
  __shared__ int s_i0[8][32], s_i1[8][32];
  {
    int base = row * 96;
    float lg = P[base + 64 + hp] + P[PSZF + base + 64 + hp];
    float mx = fmaxf(lg, __shfl_xor(lg, 1));
    mx = fmaxf(mx, __shfl_xor(mx, 2));
    float e = __expf(lg - mx);
    float s = e + __shfl_xor(e, 1);
    s = s + __shfl_xor(s, 2);
    float aw = e / s;

    float ox = P[base + 2 * hp] + P[PSZF + base + 2 * hp];
    float oy = P[base + 2 * hp + 1] + P[PSZF + base + 2 * hp + 1];
    float refy = (float)l * (1.0f / 2047.0f);
    float lx = fminf(fmaxf(ox, 0.0f), 1.0f);
    float ly = fminf(fmaxf(oy + refy, 0.0f), 1.0f);
    float ix = ((lx + 1.0f) * 2048.0f - 1.0f) * 0.5f;
    float ywt = 1.0f - ly * 0.5f;
    float ix0 = floorf(ix);
    float fx = ix - ix0;
    int i0 = (int)ix0;
    int i1 = i0 + 1;
    s_w0[rr][hp] = aw * ywt * (1.0f - fx);
    s_w1[rr][hp] = (i1 < 2048) ? (aw * ywt * fx) : 0.0f;
    s_i0[rr][hp] = i0;
    s_i1[rr][hp] = (i1 < 2048) ? i1 : 2047;
  }
  __syncthreads();

  int b = (blockIdx.x * 8) >> 11;                 // 8 rows never cross a batch
  int h = tid >> 5, c = (tid & 31) << 1;
  const unsigned short* vhc = v + ((size_t)(b << 11)) * 512 + h * 64 + c;
#pragma unroll
  for (int r8 = 0; r8 < 8; r8++) {
    int row2 = blockIdx.x * 8 + r8;
    float ax = 0.0f, ay = 0.0f;
#pragma unroll
    for (int p = 0; p < 4; p++) {
      int t = (h << 2) + p;
      unsigned g0 = *(const unsigned*)(vhc + ((size_t)s_i0[r8][t] << 9));
      unsigned g1 = *(const unsigned*)(vhc + ((size_t)s_i1[r8][t] << 9));
      float w0 = s_w0[r8][t], w1 = s_w1[r8][t];
      ax += w0 * bf2f((unsigned short)g0) + w1 * bf2f((unsigned short)g1);
      ay += w0 * bf2f((unsigned short)(g0 >> 16)) + w1 * bf2f((unsigned short)(g1 >> 16));
    }
    unsigned packed = (unsigned)f2bf(ax) | ((unsigned)f2bf(ay) << 16);
    *(unsigned*)(attn + (size_t)row2 * 512 + h * 64 + c) = packed;
  }
}

// ---------------- host launcher ----------------
extern "C" void kernel_launch(void* const* d_in, const int* in_sizes, int n_in,
                              void* d_out, int out_size, void* d_ws, size_t ws_size,
                              hipStream_t stream) {
  (void)in_sizes; (void)n_in; (void)out_size; (void)ws_size;
  const float* query = (const float*)d_in[0];
  // d_in[1] = key_in : unused by the reference
  const float* value = (const float*)d_in[2];
  const float* W_v   = (const float*)d_in[3];
  const float* b_v   = (const float*)d_in[4];
  const float* W_off = (const float*)d_in[5];
  const float* b_off = (const float*)d_in[6];
  const float* W_aw  = (const float*)d_in[7];
  const float* b_aw  = (const float*)d_in[8];
  const float* W_out = (const float*)d_in[9];
  const float* b_out = (const float*)d_in[10];
  float* out = (float*)d_out;

  char* ws = (char*)d_ws;
  const size_t MB = 1ull << 20;
  unsigned short* attn   = (unsigned short*)(ws);                  // 16 MB (attn bf16)
  unsigned short* v_bf   = (unsigned short*)(ws + 16 * MB);        // 16 MB (v projection)
  float* offP            = (float*)(ws + 32 * MB);                 // 2 x 6 MB offaw partials
  unsigned short* Wv_t   = (unsigned short*)(ws + 48 * MB);        // 0.5 MB
  unsigned short* Wo_t   = (unsigned short*)(ws + 48 * MB + 524288);
  unsigned short* Bhi    = (unsigned short*)(ws + 49 * MB);        // 96 KB
  unsigned short* Blo    = (unsigned short*)(ws + 49 * MB + 98304);

  // K0: weight prep only (573,440 threads = 2240 blocks)
  prep_all<<<2240, 256, 0, stream>>>(W_v, W_out, W_off, W_aw, Wv_t, Wo_t, Bhi, Blo);
  // K1: v = value@W_v + b_v (barrier-free reg-GEMM)  ||  offaw split-bf16
  mega_k1<<<1024, 256, 0, stream>>>(value, Wv_t, b_v, v_bf, query, Bhi, Blo,
                                    b_off, b_aw, offP);
  // K2: softmax + grid-sample gather -> attn (bf16)
  sample_kernel<<<2048, 256, 0, stream>>>(offP, v_bf, attn);
  // K3: out = attn @ W_out + b_out (barrier-free reg-GEMM, fp32 out)
  gemm2_k<<<512, 256, 0, stream>>>(attn, Wo_t, b_out, out);
}

// Round 7
// 194.301 us; speedup vs baseline: 1.2150x; 1.2150x over previous
//
#include <hip/hip_runtime.h>
#include <stdint.h>

// Problem: B=8, L=2048, D=512, H=8, P=4, C=64.  M = B*L = 16384.
#define PSZF (16384 * 96)   // elements per offaw partial buffer (split-K half)

using short8  = __attribute__((ext_vector_type(8))) short;
using floatx4 = __attribute__((ext_vector_type(4))) float;

__device__ __forceinline__ unsigned short f2bf(float f) {  // RNE
  union { float f; unsigned u; } v; v.f = f;
  unsigned r = v.u + 0x7fffu + ((v.u >> 16) & 1u);
  return (unsigned short)(r >> 16);
}
__device__ __forceinline__ float bf2f(unsigned short u) {
  union { unsigned u; float f; } v; v.u = ((unsigned)u) << 16; return v.f;
}

__device__ __forceinline__ void load_lds16(const void* g, void* l) {
  __builtin_amdgcn_global_load_lds(
      (const __attribute__((address_space(1))) unsigned int*)g,
      (__attribute__((address_space(3))) unsigned int*)l, 16, 0, 0);
}

__device__ __forceinline__ short8 cvt8(float4 a, float4 b) {
  short8 r;
  r[0] = (short)f2bf(a.x); r[1] = (short)f2bf(a.y);
  r[2] = (short)f2bf(a.z); r[3] = (short)f2bf(a.w);
  r[4] = (short)f2bf(b.x); r[5] = (short)f2bf(b.y);
  r[6] = (short)f2bf(b.z); r[7] = (short)f2bf(b.w);
  return r;
}

// ---------------- K0: weight prep only (value conversion fused into K1) -----------
__global__ __launch_bounds__(256) void prep_all(const float* __restrict__ W_v,
                                                const float* __restrict__ W_out,
                                                const float* __restrict__ Woff,
                                                const float* __restrict__ Waw,
                                                unsigned short* __restrict__ Wv_t,
                                                unsigned short* __restrict__ Wo_t,
                                                unsigned short* __restrict__ Bhi,
                                                unsigned short* __restrict__ Blo) {
  int t = blockIdx.x * 256 + threadIdx.x;
  if (t < 262144) {
    int n = t >> 9, k = t & 511;
    Wv_t[t] = f2bf(W_v[(k << 9) + n]);
    return;
  }
  t -= 262144;
  if (t < 262144) {
    int n = t >> 9, k = t & 511;
    Wo_t[t] = f2bf(W_out[(k << 9) + n]);
    return;
  }
  t -= 262144;
  if (t < 49152) {
    int n = t >> 9, k = t & 511;
    float w = (n < 64) ? Woff[(k << 6) + n] : Waw[(k << 5) + (n - 64)];
    unsigned short hi = f2bf(w);
    Bhi[t] = hi;
    Blo[t] = f2bf(w - bf2f(hi));
  }
}

// ---------------- K3 GEMM body: 128x128 tile, BK=64, bf16 A (R1/R5-proven) --------
__device__ __forceinline__ void gemm_body64_bf16A(unsigned char* smem,
                                                  const unsigned short* __restrict__ A,
                                                  const unsigned short* __restrict__ Bt,
                                                  const float* __restrict__ bias,
                                                  float* __restrict__ C, int bx, int by) {
  unsigned short* lA = (unsigned short*)smem;            // 2 chunks x 8 KB
  unsigned short* lB = (unsigned short*)(smem + 16384);  // 2 chunks x 8 KB
  int tid  = threadIdx.x;
  int lane = tid & 63, wv = tid >> 6;
  int wm = wv & 1, wn = wv >> 1;
  int lrow = lane & 15, quad = lane >> 4;
  int rowBlk = by * 128, colBlk = bx * 128;

  const unsigned short* Ab = A + (size_t)rowBlk * 512;
  const unsigned short* Bb = Bt + (size_t)colBlk * 512;
  int r0 = tid >> 2;            // 0..63
  int c0 = (tid & 3) << 3;      // 0,8,16,24

  floatx4 acc[4][4];
#pragma unroll
  for (int i = 0; i < 4; i++)
#pragma unroll
    for (int j = 0; j < 4; j++) acc[i][j] = (floatx4){0.f, 0.f, 0.f, 0.f};

  for (int k0 = 0; k0 < 512; k0 += 64) {
    load_lds16(Ab + (size_t)r0 * 512 + k0 + c0,             lA + tid * 8);
    load_lds16(Ab + (size_t)(r0 + 64) * 512 + k0 + c0,      lA + 2048 + tid * 8);
    load_lds16(Bb + (size_t)r0 * 512 + k0 + c0,             lB + tid * 8);
    load_lds16(Bb + (size_t)(r0 + 64) * 512 + k0 + c0,      lB + 2048 + tid * 8);
    load_lds16(Ab + (size_t)r0 * 512 + k0 + 32 + c0,        lA + 4096 + tid * 8);
    load_lds16(Ab + (size_t)(r0 + 64) * 512 + k0 + 32 + c0, lA + 6144 + tid * 8);
    load_lds16(Bb + (size_t)r0 * 512 + k0 + 32 + c0,        lB + 4096 + tid * 8);
    load_lds16(Bb + (size_t)(r0 + 64) * 512 + k0 + 32 + c0, lB + 6144 + tid * 8);
    __syncthreads();

#pragma unroll
    for (int kc = 0; kc < 2; kc++) {
      short8 a[4], b[4];
#pragma unroll
      for (int mi = 0; mi < 4; mi++)
        a[mi] = *(const short8*)&lA[kc * 4096 + (wm * 64 + mi * 16 + lrow) * 32 + quad * 8];
#pragma unroll
      for (int ni = 0; ni < 4; ni++)
        b[ni] = *(const short8*)&lB[kc * 4096 + (wn * 64 + ni * 16 + lrow) * 32 + quad * 8];
#pragma unroll
      for (int mi = 0; mi < 4; mi++)
#pragma unroll
        for (int ni = 0; ni < 4; ni++)
          acc[mi][ni] = __builtin_amdgcn_mfma_f32_16x16x32_bf16(a[mi], b[ni], acc[mi][ni], 0, 0, 0);
    }
    __syncthreads();
  }

  // C/D layout: col = lane&15, row = quad*4 + reg   [verified m89/m91]
#pragma unroll
  for (int ni = 0; ni < 4; ni++) {
    int col = colBlk + wn * 64 + ni * 16 + lrow;
    float bv = bias[col];
#pragma unroll
    for (int mi = 0; mi < 4; mi++) {
      int row = rowBlk + wm * 64 + mi * 16 + quad * 4;
#pragma unroll
      for (int r = 0; r < 4; r++)
        C[(size_t)(row + r) * 512 + col] = acc[mi][ni][r] + bv;
    }
  }
}

// ---------------- K1 gemm1 body: 128x64 tile, BK=64, fp32 A, T14 prefetch ---------
// Half-size blocks (vs R5's 128x128) -> 1024 gemm blocks, acc 32 AGPR (was 64),
// LDS 24 KB (was 32): more co-resident blocks/CU so each block's barrier stall
// overlaps other blocks' compute (m114 mechanism).  Inner step keeps R5's exact
// staging: A fp32 prefetched one tile early in regs (T14), B via 2 gload_lds,
// counted vmcnt(8) drains B only, raw barriers.  Bit-identical numerics.
__device__ __forceinline__ void gemm_n64_f32A(unsigned char* smem,
                                              const float* __restrict__ Af,
                                              const unsigned short* __restrict__ Bt,
                                              const float* __restrict__ bias,
                                              unsigned short* __restrict__ C,
                                              int bx, int by) {
  unsigned short* lA = (unsigned short*)smem;            // 2 chunks x 8 KB = 16 KB
  unsigned short* lB = (unsigned short*)(smem + 16384);  // 2 chunks x 4 KB = 8 KB
  int tid  = threadIdx.x;
  int lane = tid & 63, wv = tid >> 6;
  int wm = wv & 1, wn = wv >> 1;          // 2 row-strips x 2 col-strips
  int lrow = lane & 15, quad = lane >> 4;
  int rowBlk = by * 128, colBlk = bx * 64;

  const unsigned short* Bb = Bt + (size_t)colBlk * 512;
  int r0 = tid >> 2;            // 0..63
  int c0 = (tid & 3) << 3;      // 0,8,16,24
  const float* Ar0 = Af + (size_t)(rowBlk + r0) * 512 + c0;
  const float* Ar1 = Af + (size_t)(rowBlk + r0 + 64) * 512 + c0;

  floatx4 acc[4][2];
#pragma unroll
  for (int i = 0; i < 4; i++)
#pragma unroll
    for (int j = 0; j < 2; j++) acc[i][j] = (floatx4){0.f, 0.f, 0.f, 0.f};

  // prologue: issue A(k0=0)
  float4 a00 = *(const float4*)(Ar0);
  float4 a01 = *(const float4*)(Ar0 + 4);
  float4 a10 = *(const float4*)(Ar1);
  float4 a11 = *(const float4*)(Ar1 + 4);
  float4 a02 = *(const float4*)(Ar0 + 32);
  float4 a03 = *(const float4*)(Ar0 + 36);
  float4 a12 = *(const float4*)(Ar1 + 32);
  float4 a13 = *(const float4*)(Ar1 + 36);

  for (int k0 = 0; k0 < 512; k0 += 64) {
    // B stage: 64 out-cols x 64 k, 2 chunks of [64][32]
    load_lds16(Bb + (size_t)r0 * 512 + k0 + c0,      lB + tid * 8);
    load_lds16(Bb + (size_t)r0 * 512 + k0 + 32 + c0, lB + 2048 + tid * 8);
    // cvt A(k0) from regs (issued one tile ago) + LDS write
    *(short8*)&lA[tid * 8]        = cvt8(a00, a01);
    *(short8*)&lA[2048 + tid * 8] = cvt8(a10, a11);
    *(short8*)&lA[4096 + tid * 8] = cvt8(a02, a03);
    *(short8*)&lA[6144 + tid * 8] = cvt8(a12, a13);
    if (k0 < 448) {
      int kk = k0 + 64;
      a00 = *(const float4*)(Ar0 + kk);
      a01 = *(const float4*)(Ar0 + kk + 4);
      a10 = *(const float4*)(Ar1 + kk);
      a11 = *(const float4*)(Ar1 + kk + 4);
      a02 = *(const float4*)(Ar0 + kk + 32);
      a03 = *(const float4*)(Ar0 + kk + 36);
      a12 = *(const float4*)(Ar1 + kk + 32);
      a13 = *(const float4*)(Ar1 + kk + 36);
      asm volatile("s_waitcnt vmcnt(8)" ::: "memory");   // drain B(2); keep A(next) 8
    } else {
      asm volatile("s_waitcnt vmcnt(0)" ::: "memory");
    }
    asm volatile("s_waitcnt lgkmcnt(0)" ::: "memory");
    __builtin_amdgcn_sched_barrier(0);
    __builtin_amdgcn_s_barrier();
    __builtin_amdgcn_sched_barrier(0);

#pragma unroll
    for (int kc = 0; kc < 2; kc++) {
      short8 a[4], b[2];
#pragma unroll
      for (int mi = 0; mi < 4; mi++)
        a[mi] = *(const short8*)&lA[kc * 4096 + (wm * 64 + mi * 16 + lrow) * 32 + quad * 8];
#pragma unroll
      for (int ni = 0; ni < 2; ni++)
        b[ni] = *(const short8*)&lB[kc * 2048 + (wn * 32 + ni * 16 + lrow) * 32 + quad * 8];
#pragma unroll
      for (int mi = 0; mi < 4; mi++)
#pragma unroll
        for (int ni = 0; ni < 2; ni++)
          acc[mi][ni] = __builtin_amdgcn_mfma_f32_16x16x32_bf16(a[mi], b[ni], acc[mi][ni], 0, 0, 0);
    }
    __builtin_amdgcn_sched_barrier(0);
    __builtin_amdgcn_s_barrier();
  }

#pragma unroll
  for (int ni = 0; ni < 2; ni++) {
    int col = colBlk + wn * 32 + ni * 16 + lrow;
    float bv = bias[col];
#pragma unroll
    for (int mi = 0; mi < 4; mi++) {
      int row = rowBlk + wm * 64 + mi * 16 + quad * 4;
#pragma unroll
      for (int r = 0; r < 4; r++)
        C[(size_t)(row + r) * 512 + col] = f2bf(acc[mi][ni][r] + bv);
    }
  }
}

// XCD swizzle for K3's 512 blocks (128x128): bx 0..3, by 0..127.
__device__ __forceinline__ void swz512(int bid, int& bx, int& by) {
  int x = bid & 7, s = bid >> 3;
  by = (x << 4) | (s >> 2);
  bx = s & 3;
}
// XCD swizzle for K1's 1024 gemm blocks (128x64): bx 0..7, by 0..127.
// The 8 bx-siblings of one 128-row A-band land on one XCD consecutively
// -> the band's 256 KB fp32 stays L2-hot across them.
__device__ __forceinline__ void swzg(int bid, int& bx, int& by) {
  int x = bid & 7, s = bid >> 3;            // s 0..127
  by = (x << 4) | (s >> 3);                 // 0..127
  bx = s & 7;                               // 0..7
}

// ---------------- offaw body: split-bf16 + T14 Q-prefetch + counted vmcnt (R5) ----
__device__ __forceinline__ void offaw_body(unsigned char* smem,
                                           const float* __restrict__ Q,
                                           const unsigned short* __restrict__ Bhi,
                                           const unsigned short* __restrict__ Blo,
                                           const float* __restrict__ boff,
                                           const float* __restrict__ baw,
                                           float* __restrict__ P, int bid) {
  unsigned short* lAhi = (unsigned short*)smem;            // 64*32 = 4 KB
  unsigned short* lAlo = (unsigned short*)(smem + 4096);   // 4 KB
  unsigned short* lBhi = (unsigned short*)(smem + 8192);   // 96*32 = 6 KB
  unsigned short* lBlo = (unsigned short*)(smem + 14336);  // 6 KB (ends at 20480)
  int khalf = bid >> 8, row0 = (bid & 255) * 64, kbase = khalf << 8;
  int tid = threadIdx.x, lane = tid & 63, wv = tid >> 6;
  int wm = wv & 1, wn = wv >> 1, lrow = lane & 15, quad = lane >> 4;

  int ar = tid >> 2, ac = (tid & 3) << 3;
  const float* qp = Q + (size_t)(row0 + ar) * 512 + kbase + ac;

  floatx4 acc[2][3];
#pragma unroll
  for (int i = 0; i < 2; i++)
#pragma unroll
    for (int j = 0; j < 3; j++) acc[i][j] = (floatx4){0.f, 0.f, 0.f, 0.f};

  // prologue: issue Q(k0=0)
  float4 v0 = *(const float4*)(qp);
  float4 v1 = *(const float4*)(qp + 4);

  for (int k0 = 0; k0 < 256; k0 += 32) {
    // B stage first (3 gload_lds, wave-uniform routing)
#pragma unroll
    for (int j = 0; j < 3; j++) {
      int widx = wv + (j << 2);                        // 0..11, wave-uniform
      const unsigned short* src = (widx < 6) ? Bhi : Blo;
      unsigned short* dst = (widx < 6) ? lBhi : lBlo;
      int c = (((widx < 6) ? widx : widx - 6) << 6) + lane;  // 0..383
      int n = c >> 2, cc = (c & 3) << 3;
      load_lds16(src + (size_t)n * 512 + kbase + k0 + cc, dst + c * 8);
    }
    // split-bf16 cvt of Q(k0) from prefetched regs
    {
      float vv[8] = {v0.x, v0.y, v0.z, v0.w, v1.x, v1.y, v1.z, v1.w};
      short8 h8, l8;
#pragma unroll
      for (int e = 0; e < 8; e++) {
        union { float f; unsigned u; } t; t.f = vv[e];
        unsigned r = t.u + 0x7fffu + ((t.u >> 16) & 1u);
        h8[e] = (short)(r >> 16);
        union { unsigned u; float f; } hf; hf.u = r & 0xffff0000u;
        union { float f; unsigned u; } rb; rb.f = vv[e] - hf.f;
        l8[e] = (short)(rb.u >> 16);
      }
      *(short8*)&lAhi[tid * 8] = h8;
      *(short8*)&lAlo[tid * 8] = l8;
    }
    if (k0 < 224) {
      v0 = *(const float4*)(qp + k0 + 32);
      v1 = *(const float4*)(qp + k0 + 36);
      asm volatile("s_waitcnt vmcnt(2)" ::: "memory");   // drain B3; keep Q(next) 2
    } else {
      asm volatile("s_waitcnt vmcnt(0)" ::: "memory");
    }
    asm volatile("s_waitcnt lgkmcnt(0)" ::: "memory");
    __builtin_amdgcn_sched_barrier(0);
    __builtin_amdgcn_s_barrier();
    __builtin_amdgcn_sched_barrier(0);

    short8 ah[2], al[2], bh[3], bl[3];
#pragma unroll
    for (int mi = 0; mi < 2; mi++) {
      int r = (wm * 32 + mi * 16 + lrow) * 32 + quad * 8;
      ah[mi] = *(const short8*)&lAhi[r];
      al[mi] = *(const short8*)&lAlo[r];
    }
#pragma unroll
    for (int ni = 0; ni < 3; ni++) {
      int r = (wn * 48 + ni * 16 + lrow) * 32 + quad * 8;
      bh[ni] = *(const short8*)&lBhi[r];
      bl[ni] = *(const short8*)&lBlo[r];
    }
#pragma unroll
    for (int mi = 0; mi < 2; mi++)
#pragma unroll
      for (int ni = 0; ni < 3; ni++) {
        acc[mi][ni] = __builtin_amdgcn_mfma_f32_16x16x32_bf16(ah[mi], bh[ni], acc[mi][ni], 0, 0, 0);
        acc[mi][ni] = __builtin_amdgcn_mfma_f32_16x16x32_bf16(ah[mi], bl[ni], acc[mi][ni], 0, 0, 0);
        acc[mi][ni] = __builtin_amdgcn_mfma_f32_16x16x32_bf16(al[mi], bh[ni], acc[mi][ni], 0, 0, 0);
      }
    __builtin_amdgcn_sched_barrier(0);
    __builtin_amdgcn_s_barrier();
  }

  float* out = P + (size_t)khalf * PSZF;
#pragma unroll
  for (int ni = 0; ni < 3; ni++) {
    int col = wn * 48 + ni * 16 + lrow;
    float bv = (khalf == 0) ? ((col < 64) ? boff[col] : baw[col - 64]) : 0.0f;
#pragma unroll
    for (int mi = 0; mi < 2; mi++) {
      int row = row0 + wm * 32 + mi * 16 + quad * 4;
#pragma unroll
      for (int r = 0; r < 4; r++)
        out[(size_t)(row + r) * 96 + col] = acc[mi][ni][r] + bv;
    }
  }
}

// ---------------- K1: gemm1 (1024 x 128x64 blocks) + offaw (512 blocks) -----------
__global__ __launch_bounds__(256) void mega_k1(const float* __restrict__ value,
                                               const unsigned short* __restrict__ Wv_t,
                                               const float* __restrict__ b_v,
                                               unsigned short* __restrict__ v_bf,
                                               const float* __restrict__ query,
                                               const unsigned short* __restrict__ Bhi,
                                               const unsigned short* __restrict__ Blo,
                                               const float* __restrict__ boff,
                                               const float* __restrict__ baw,
                                               float* __restrict__ offP) {
  __shared__ __align__(16) unsigned char smem[24576];
  int bid = blockIdx.x;
  if (bid < 1024) {
    int bx, by; swzg(bid, bx, by);
    gemm_n64_f32A(smem, value, Wv_t, b_v, v_bf, bx, by);
  } else {
    offaw_body(smem, query, Bhi, Blo, boff, baw, offP, bid - 1024);
  }
}

// ---------------- K3: out = attn @ W_out + b_out (512 blocks, swizzled) -----------
__global__ __launch_bounds__(256) void gemm2_k(const unsigned short* __restrict__ A,
                                               const unsigned short* __restrict__ Bt,
                                               const float* __restrict__ bias,
                                               float* __restrict__ C) {
  __shared__ __align__(16) unsigned char smem[32768];
  int bx, by; swz512(blockIdx.x, bx, by);
  gemm_body64_bf16A(smem, A, Bt, bias, C, bx, by);
}

// ---------------- K2: fused softmax + 1-D grid-sample gather ----------------------
__global__ __launch_bounds__(256) void sample_kernel(const float* __restrict__ P,
                                                     const unsigned short* __restrict__ v,
                                                     unsigned short* __restrict__ attn) {
  int tid = threadIdx.x;
  int rr = tid >> 5, hp = tid & 31;
  int row = blockIdx.x * 8 + rr;
  int l = row & 2047;
  __shared__ float s_w0[8][32], s_w1[8][32];
  __shared__ int s_i0[8][32], s_i1[8][32];
  {
    int base = row * 96;
    float lg = P[base + 64 + hp] + P[PSZF + base + 64 + hp];
    float mx = fmaxf(lg, __shfl_xor(lg, 1));
    mx = fmaxf(mx, __shfl_xor(mx, 2));
    float e = __expf(lg - mx);
    float s = e + __shfl_xor(e, 1);
    s = s + __shfl_xor(s, 2);
    float aw = e / s;

    float ox = P[base + 2 * hp] + P[PSZF + base + 2 * hp];
    float oy = P[base + 2 * hp + 1] + P[PSZF + base + 2 * hp + 1];
    float refy = (float)l * (1.0f / 2047.0f);
    float lx = fminf(fmaxf(ox, 0.0f), 1.0f);
    float ly = fminf(fmaxf(oy + refy, 0.0f), 1.0f);
    float ix = ((lx + 1.0f) * 2048.0f - 1.0f) * 0.5f;
    float ywt = 1.0f - ly * 0.5f;
    float ix0 = floorf(ix);
    float fx = ix - ix0;
    int i0 = (int)ix0;
    int i1 = i0 + 1;
    s_w0[rr][hp] = aw * ywt * (1.0f - fx);
    s_w1[rr][hp] = (i1 < 2048) ? (aw * ywt * fx) : 0.0f;
    s_i0[rr][hp] = i0;
    s_i1[rr][hp] = (i1 < 2048) ? i1 : 2047;
  }
  __syncthreads();

  int b = (blockIdx.x * 8) >> 11;                 // 8 rows never cross a batch
  int h = tid >> 5, c = (tid & 31) << 1;
  const unsigned short* vhc = v + ((size_t)(b << 11)) * 512 + h * 64 + c;
#pragma unroll
  for (int r8 = 0; r8 < 8; r8++) {
    int row2 = blockIdx.x * 8 + r8;
    float ax = 0.0f, ay = 0.0f;
#pragma unroll
    for (int p = 0; p < 4; p++) {
      int t = (h << 2) + p;
      unsigned g0 = *(const unsigned*)(vhc + ((size_t)s_i0[r8][t] << 9));
      unsigned g1 = *(const unsigned*)(vhc + ((size_t)s_i1[r8][t] << 9));
      float w0 = s_w0[r8][t], w1 = s_w1[r8][t];
      ax += w0 * bf2f((unsigned short)g0) + w1 * bf2f((unsigned short)g1);
      ay += w0 * bf2f((unsigned short)(g0 >> 16)) + w1 * bf2f((unsigned short)(g1 >> 16));
    }
    unsigned packed = (unsigned)f2bf(ax) | ((unsigned)f2bf(ay) << 16);
    *(unsigned*)(attn + (size_t)row2 * 512 + h * 64 + c) = packed;
  }
}

// ---------------- host launcher ----------------
extern "C" void kernel_launch(void* const* d_in, const int* in_sizes, int n_in,
                              void* d_out, int out_size, void* d_ws, size_t ws_size,
                              hipStream_t stream) {
  (void)in_sizes; (void)n_in; (void)out_size; (void)ws_size;
  const float* query = (const float*)d_in[0];
  // d_in[1] = key_in : unused by the reference
  const float* value = (const float*)d_in[2];
  const float* W_v   = (const float*)d_in[3];
  const float* b_v   = (const float*)d_in[4];
  const float* W_off = (const float*)d_in[5];
  const float* b_off = (const float*)d_in[6];
  const float* W_aw  = (const float*)d_in[7];
  const float* b_aw  = (const float*)d_in[8];
  const float* W_out = (const float*)d_in[9];
  const float* b_out = (const float*)d_in[10];
  float* out = (float*)d_out;

  char* ws = (char*)d_ws;
  const size_t MB = 1ull << 20;
  unsigned short* attn   = (unsigned short*)(ws);                  // 16 MB (attn bf16)
  unsigned short* v_bf   = (unsigned short*)(ws + 16 * MB);        // 16 MB (v projection)
  float* offP            = (float*)(ws + 32 * MB);                 // 2 x 6 MB offaw partials
  unsigned short* Wv_t   = (unsigned short*)(ws + 48 * MB);        // 0.5 MB
  unsigned short* Wo_t   = (unsigned short*)(ws + 48 * MB + 524288);
  unsigned short* Bhi    = (unsigned short*)(ws + 49 * MB);        // 96 KB
  unsigned short* Blo    = (unsigned short*)(ws + 49 * MB + 98304);

  // K0: weight prep only (573,440 threads = 2240 blocks)
  prep_all<<<2240, 256, 0, stream>>>(W_v, W_out, W_off, W_aw, Wv_t, Wo_t, Bhi, Blo);
  // K1: v = value@W_v + b_v (1024 x 128x64 staged blocks)  ||  offaw split-bf16
  mega_k1<<<1536, 256, 0, stream>>>(value, Wv_t, b_v, v_bf, query, Bhi, Blo,
                                    b_off, b_aw, offP);
  // K2: softmax + grid-sample gather -> attn (bf16)
  sample_kernel<<<2048, 256, 0, stream>>>(offP, v_bf, attn);
  // K3: out = attn @ W_out + b_out (fp32 out)
  gemm2_k<<<512, 256, 0, stream>>>(attn, Wo_t, b_out, out);
}

// Round 8
// 187.982 us; speedup vs baseline: 1.2559x; 1.0336x over previous
//
#include <hip/hip_runtime.h>
#include <stdint.h>

// Problem: B=8, L=2048, D=512, H=8, P=4, C=64.  M = B*L = 16384.
#define PSZF (16384 * 96)   // elements per offaw partial buffer (split-K half)

using short8  = __attribute__((ext_vector_type(8))) short;
using floatx4 = __attribute__((ext_vector_type(4))) float;

__device__ __forceinline__ unsigned short f2bf(float f) {  // RNE
  union { float f; unsigned u; } v; v.f = f;
  unsigned r = v.u + 0x7fffu + ((v.u >> 16) & 1u);
  return (unsigned short)(r >> 16);
}
__device__ __forceinline__ float bf2f(unsigned short u) {
  union { unsigned u; float f; } v; v.u = ((unsigned)u) << 16; return v.f;
}

__device__ __forceinline__ void load_lds16(const void* g, void* l) {
  __builtin_amdgcn_global_load_lds(
      (const __attribute__((address_space(1))) unsigned int*)g,
      (__attribute__((address_space(3))) unsigned int*)l, 16, 0, 0);
}

__device__ __forceinline__ short8 cvt8(float4 a, float4 b) {
  short8 r;
  r[0] = (short)f2bf(a.x); r[1] = (short)f2bf(a.y);
  r[2] = (short)f2bf(a.z); r[3] = (short)f2bf(a.w);
  r[4] = (short)f2bf(b.x); r[5] = (short)f2bf(b.y);
  r[6] = (short)f2bf(b.z); r[7] = (short)f2bf(b.w);
  return r;
}

// ---------------- K0: weight prep only (value conversion fused into K1) -----------
__global__ __launch_bounds__(256) void prep_all(const float* __restrict__ W_v,
                                                const float* __restrict__ W_out,
                                                const float* __restrict__ Woff,
                                                const float* __restrict__ Waw,
                                                unsigned short* __restrict__ Wv_t,
                                                unsigned short* __restrict__ Wo_t,
                                                unsigned short* __restrict__ Bhi,
                                                unsigned short* __restrict__ Blo) {
  int t = blockIdx.x * 256 + threadIdx.x;
  if (t < 262144) {
    int n = t >> 9, k = t & 511;
    Wv_t[t] = f2bf(W_v[(k << 9) + n]);
    return;
  }
  t -= 262144;
  if (t < 262144) {
    int n = t >> 9, k = t & 511;
    Wo_t[t] = f2bf(W_out[(k << 9) + n]);
    return;
  }
  t -= 262144;
  if (t < 49152) {
    int n = t >> 9, k = t & 511;
    float w = (n < 64) ? Woff[(k << 6) + n] : Waw[(k << 5) + (n - 64)];
    unsigned short hi = f2bf(w);
    Bhi[t] = hi;
    Blo[t] = f2bf(w - bf2f(hi));
  }
}

// ---------------- K3 GEMM body: 128x128 tile, BK=64, bf16 A (R1/R5-proven) --------
// + T5 setprio around the compute phase.
__device__ __forceinline__ void gemm_body64_bf16A(unsigned char* smem,
                                                  const unsigned short* __restrict__ A,
                                                  const unsigned short* __restrict__ Bt,
                                                  const float* __restrict__ bias,
                                                  float* __restrict__ C, int bx, int by) {
  unsigned short* lA = (unsigned short*)smem;            // 2 chunks x 8 KB
  unsigned short* lB = (unsigned short*)(smem + 16384);  // 2 chunks x 8 KB
  int tid  = threadIdx.x;
  int lane = tid & 63, wv = tid >> 6;
  int wm = wv & 1, wn = wv >> 1;
  int lrow = lane & 15, quad = lane >> 4;
  int rowBlk = by * 128, colBlk = bx * 128;

  const unsigned short* Ab = A + (size_t)rowBlk * 512;
  const unsigned short* Bb = Bt + (size_t)colBlk * 512;
  int r0 = tid >> 2;            // 0..63
  int c0 = (tid & 3) << 3;      // 0,8,16,24

  floatx4 acc[4][4];
#pragma unroll
  for (int i = 0; i < 4; i++)
#pragma unroll
    for (int j = 0; j < 4; j++) acc[i][j] = (floatx4){0.f, 0.f, 0.f, 0.f};

  for (int k0 = 0; k0 < 512; k0 += 64) {
    load_lds16(Ab + (size_t)r0 * 512 + k0 + c0,             lA + tid * 8);
    load_lds16(Ab + (size_t)(r0 + 64) * 512 + k0 + c0,      lA + 2048 + tid * 8);
    load_lds16(Bb + (size_t)r0 * 512 + k0 + c0,             lB + tid * 8);
    load_lds16(Bb + (size_t)(r0 + 64) * 512 + k0 + c0,      lB + 2048 + tid * 8);
    load_lds16(Ab + (size_t)r0 * 512 + k0 + 32 + c0,        lA + 4096 + tid * 8);
    load_lds16(Ab + (size_t)(r0 + 64) * 512 + k0 + 32 + c0, lA + 6144 + tid * 8);
    load_lds16(Bb + (size_t)r0 * 512 + k0 + 32 + c0,        lB + 4096 + tid * 8);
    load_lds16(Bb + (size_t)(r0 + 64) * 512 + k0 + 32 + c0, lB + 6144 + tid * 8);
    __syncthreads();

    __builtin_amdgcn_s_setprio(1);
#pragma unroll
    for (int kc = 0; kc < 2; kc++) {
      short8 a[4], b[4];
#pragma unroll
      for (int mi = 0; mi < 4; mi++)
        a[mi] = *(const short8*)&lA[kc * 4096 + (wm * 64 + mi * 16 + lrow) * 32 + quad * 8];
#pragma unroll
      for (int ni = 0; ni < 4; ni++)
        b[ni] = *(const short8*)&lB[kc * 4096 + (wn * 64 + ni * 16 + lrow) * 32 + quad * 8];
#pragma unroll
      for (int mi = 0; mi < 4; mi++)
#pragma unroll
        for (int ni = 0; ni < 4; ni++)
          acc[mi][ni] = __builtin_amdgcn_mfma_f32_16x16x32_bf16(a[mi], b[ni], acc[mi][ni], 0, 0, 0);
    }
    __builtin_amdgcn_s_setprio(0);
    __syncthreads();
  }

  // C/D layout: col = lane&15, row = quad*4 + reg   [verified m89/m91]
#pragma unroll
  for (int ni = 0; ni < 4; ni++) {
    int col = colBlk + wn * 64 + ni * 16 + lrow;
    float bv = bias[col];
#pragma unroll
    for (int mi = 0; mi < 4; mi++) {
      int row = rowBlk + wm * 64 + mi * 16 + quad * 4;
#pragma unroll
      for (int r = 0; r < 4; r++)
        C[(size_t)(row + r) * 512 + col] = acc[mi][ni][r] + bv;
    }
  }
}

// ---------------- fp32-A body with T14 prefetch + counted vmcnt + T5 (K1 gemm1) ---
__device__ __forceinline__ void gemm_body64_f32A(unsigned char* smem,
                                                 const float* __restrict__ Af,
                                                 const unsigned short* __restrict__ Bt,
                                                 const float* __restrict__ bias,
                                                 unsigned short* __restrict__ C, int bx, int by) {
  unsigned short* lA = (unsigned short*)smem;            // 16 KB
  unsigned short* lB = (unsigned short*)(smem + 16384);  // 16 KB
  int tid  = threadIdx.x;
  int lane = tid & 63, wv = tid >> 6;
  int wm = wv & 1, wn = wv >> 1;
  int lrow = lane & 15, quad = lane >> 4;
  int rowBlk = by * 128, colBlk = bx * 128;

  const unsigned short* Bb = Bt + (size_t)colBlk * 512;
  int r0 = tid >> 2;            // 0..63
  int c0 = (tid & 3) << 3;      // 0,8,16,24
  const float* Ar0 = Af + (size_t)(rowBlk + r0) * 512 + c0;
  const float* Ar1 = Af + (size_t)(rowBlk + r0 + 64) * 512 + c0;

  floatx4 acc[4][4];
#pragma unroll
  for (int i = 0; i < 4; i++)
#pragma unroll
    for (int j = 0; j < 4; j++) acc[i][j] = (floatx4){0.f, 0.f, 0.f, 0.f};

  // prologue: issue A(k0=0)
  float4 a00 = *(const float4*)(Ar0);
  float4 a01 = *(const float4*)(Ar0 + 4);
  float4 a10 = *(const float4*)(Ar1);
  float4 a11 = *(const float4*)(Ar1 + 4);
  float4 a02 = *(const float4*)(Ar0 + 32);
  float4 a03 = *(const float4*)(Ar0 + 36);
  float4 a12 = *(const float4*)(Ar1 + 32);
  float4 a13 = *(const float4*)(Ar1 + 36);

  for (int k0 = 0; k0 < 512; k0 += 64) {
    // B stage first (stays in flight through the cvt)
    load_lds16(Bb + (size_t)r0 * 512 + k0 + c0,             lB + tid * 8);
    load_lds16(Bb + (size_t)(r0 + 64) * 512 + k0 + c0,      lB + 2048 + tid * 8);
    load_lds16(Bb + (size_t)r0 * 512 + k0 + 32 + c0,        lB + 4096 + tid * 8);
    load_lds16(Bb + (size_t)(r0 + 64) * 512 + k0 + 32 + c0, lB + 6144 + tid * 8);
    // cvt A(k0) from regs (issued one tile ago) + LDS write
    *(short8*)&lA[tid * 8]        = cvt8(a00, a01);
    *(short8*)&lA[2048 + tid * 8] = cvt8(a10, a11);
    *(short8*)&lA[4096 + tid * 8] = cvt8(a02, a03);
    *(short8*)&lA[6144 + tid * 8] = cvt8(a12, a13);
    if (k0 < 448) {
      // issue A(k0+64): stays in flight across both barriers
      int kk = k0 + 64;
      a00 = *(const float4*)(Ar0 + kk);
      a01 = *(const float4*)(Ar0 + kk + 4);
      a10 = *(const float4*)(Ar1 + kk);
      a11 = *(const float4*)(Ar1 + kk + 4);
      a02 = *(const float4*)(Ar0 + kk + 32);
      a03 = *(const float4*)(Ar0 + kk + 36);
      a12 = *(const float4*)(Ar1 + kk + 32);
      a13 = *(const float4*)(Ar1 + kk + 36);
      asm volatile("s_waitcnt vmcnt(8)" ::: "memory");   // drain B; keep A(next) 8
    } else {
      asm volatile("s_waitcnt vmcnt(0)" ::: "memory");   // last tile: drain B
    }
    asm volatile("s_waitcnt lgkmcnt(0)" ::: "memory");   // my ds_writes visible
    __builtin_amdgcn_sched_barrier(0);
    __builtin_amdgcn_s_barrier();                        // raw: no vmcnt(0) drain
    __builtin_amdgcn_sched_barrier(0);

    __builtin_amdgcn_s_setprio(1);
#pragma unroll
    for (int kc = 0; kc < 2; kc++) {
      short8 a[4], b[4];
#pragma unroll
      for (int mi = 0; mi < 4; mi++)
        a[mi] = *(const short8*)&lA[kc * 4096 + (wm * 64 + mi * 16 + lrow) * 32 + quad * 8];
#pragma unroll
      for (int ni = 0; ni < 4; ni++)
        b[ni] = *(const short8*)&lB[kc * 4096 + (wn * 64 + ni * 16 + lrow) * 32 + quad * 8];
#pragma unroll
      for (int mi = 0; mi < 4; mi++)
#pragma unroll
        for (int ni = 0; ni < 4; ni++)
          acc[mi][ni] = __builtin_amdgcn_mfma_f32_16x16x32_bf16(a[mi], b[ni], acc[mi][ni], 0, 0, 0);
    }
    __builtin_amdgcn_s_setprio(0);
    __builtin_amdgcn_sched_barrier(0);
    __builtin_amdgcn_s_barrier();                        // all reads done before reuse
  }

#pragma unroll
  for (int ni = 0; ni < 4; ni++) {
    int col = colBlk + wn * 64 + ni * 16 + lrow;
    float bv = bias[col];
#pragma unroll
    for (int mi = 0; mi < 4; mi++) {
      int row = rowBlk + wm * 64 + mi * 16 + quad * 4;
#pragma unroll
      for (int r = 0; r < 4; r++)
        C[(size_t)(row + r) * 512 + col] = f2bf(acc[mi][ni][r] + bv);
    }
  }
}

// XCD-aware swizzle for 512-block GEMMs.
__device__ __forceinline__ void swz512(int bid, int& bx, int& by) {
  int x = bid & 7, s = bid >> 3;
  by = (x << 4) | (s >> 2);
  bx = s & 3;
}

// ---------------- offaw body: split-bf16 + T14 Q-prefetch + counted vmcnt + T5 ----
__device__ __forceinline__ void offaw_body(unsigned char* smem,
                                           const float* __restrict__ Q,
                                           const unsigned short* __restrict__ Bhi,
                                           const unsigned short* __restrict__ Blo,
                                           const float* __restrict__ boff,
                                           const float* __restrict__ baw,
                                           float* __restrict__ P, int bid) {
  unsigned short* lAhi = (unsigned short*)smem;            // 64*32 = 4 KB
  unsigned short* lAlo = (unsigned short*)(smem + 4096);   // 4 KB
  unsigned short* lBhi = (unsigned short*)(smem + 8192);   // 96*32 = 6 KB
  unsigned short* lBlo = (unsigned short*)(smem + 14336);  // 6 KB (ends at 20480)
  int khalf = bid >> 8, row0 = (bid & 255) * 64, kbase = khalf << 8;
  int tid = threadIdx.x, lane = tid & 63, wv = tid >> 6;
  int wm = wv & 1, wn = wv >> 1, lrow = lane & 15, quad = lane >> 4;

  int ar = tid >> 2, ac = (tid & 3) << 3;
  const float* qp = Q + (size_t)(row0 + ar) * 512 + kbase + ac;

  floatx4 acc[2][3];
#pragma unroll
  for (int i = 0; i < 2; i++)
#pragma unroll
    for (int j = 0; j < 3; j++) acc[i][j] = (floatx4){0.f, 0.f, 0.f, 0.f};

  // prologue: issue Q(k0=0)
  float4 v0 = *(const float4*)(qp);
  float4 v1 = *(const float4*)(qp + 4);

  for (int k0 = 0; k0 < 256; k0 += 32) {
    // B stage first (3 gload_lds, wave-uniform routing)
#pragma unroll
    for (int j = 0; j < 3; j++) {
      int widx = wv + (j << 2);                        // 0..11, wave-uniform
      const unsigned short* src = (widx < 6) ? Bhi : Blo;
      unsigned short* dst = (widx < 6) ? lBhi : lBlo;
      int c = (((widx < 6) ? widx : widx - 6) << 6) + lane;  // 0..383
      int n = c >> 2, cc = (c & 3) << 3;
      load_lds16(src + (size_t)n * 512 + kbase + k0 + cc, dst + c * 8);
    }
    // split-bf16 cvt of Q(k0) from prefetched regs
    {
      float vv[8] = {v0.x, v0.y, v0.z, v0.w, v1.x, v1.y, v1.z, v1.w};
      short8 h8, l8;
#pragma unroll
      for (int e = 0; e < 8; e++) {
        union { float f; unsigned u; } t; t.f = vv[e];
        unsigned r = t.u + 0x7fffu + ((t.u >> 16) & 1u);
        h8[e] = (short)(r >> 16);
        union { unsigned u; float f; } hf; hf.u = r & 0xffff0000u;
        union { float f; unsigned u; } rb; rb.f = vv[e] - hf.f;
        l8[e] = (short)(rb.u >> 16);
      }
      *(short8*)&lAhi[tid * 8] = h8;
      *(short8*)&lAlo[tid * 8] = l8;
    }
    if (k0 < 224) {
      v0 = *(const float4*)(qp + k0 + 32);
      v1 = *(const float4*)(qp + k0 + 36);
      asm volatile("s_waitcnt vmcnt(2)" ::: "memory");   // drain B3; keep Q(next) 2
    } else {
      asm volatile("s_waitcnt vmcnt(0)" ::: "memory");
    }
    asm volatile("s_waitcnt lgkmcnt(0)" ::: "memory");
    __builtin_amdgcn_sched_barrier(0);
    __builtin_amdgcn_s_barrier();
    __builtin_amdgcn_sched_barrier(0);

    __builtin_amdgcn_s_setprio(1);
    {
      short8 ah[2], al[2], bh[3], bl[3];
#pragma unroll
      for (int mi = 0; mi < 2; mi++) {
        int r = (wm * 32 + mi * 16 + lrow) * 32 + quad * 8;
        ah[mi] = *(const short8*)&lAhi[r];
        al[mi] = *(const short8*)&lAlo[r];
      }
#pragma unroll
      for (int ni = 0; ni < 3; ni++) {
        int r = (wn * 48 + ni * 16 + lrow) * 32 + quad * 8;
        bh[ni] = *(const short8*)&lBhi[r];
        bl[ni] = *(const short8*)&lBlo[r];
      }
#pragma unroll
      for (int mi = 0; mi < 2; mi++)
#pragma unroll
        for (int ni = 0; ni < 3; ni++) {
          acc[mi][ni] = __builtin_amdgcn_mfma_f32_16x16x32_bf16(ah[mi], bh[ni], acc[mi][ni], 0, 0, 0);
          acc[mi][ni] = __builtin_amdgcn_mfma_f32_16x16x32_bf16(ah[mi], bl[ni], acc[mi][ni], 0, 0, 0);
          acc[mi][ni] = __builtin_amdgcn_mfma_f32_16x16x32_bf16(al[mi], bh[ni], acc[mi][ni], 0, 0, 0);
        }
    }
    __builtin_amdgcn_s_setprio(0);
    __builtin_amdgcn_sched_barrier(0);
    __builtin_amdgcn_s_barrier();
  }

  float* out = P + (size_t)khalf * PSZF;
#pragma unroll
  for (int ni = 0; ni < 3; ni++) {
    int col = wn * 48 + ni * 16 + lrow;
    float bv = (khalf == 0) ? ((col < 64) ? boff[col] : baw[col - 64]) : 0.0f;
#pragma unroll
    for (int mi = 0; mi < 2; mi++) {
      int row = row0 + wm * 32 + mi * 16 + quad * 4;
#pragma unroll
      for (int r = 0; r < 4; r++)
        out[(size_t)(row + r) * 96 + col] = acc[mi][ni][r] + bv;
    }
  }
}

// ---------------- K1: gemm1 (512 blocks, swizzled, fp32 A) + offaw (512 blocks) ---
__global__ __launch_bounds__(256) void mega_k1(const float* __restrict__ value,
                                               const unsigned short* __restrict__ Wv_t,
                                               const float* __restrict__ b_v,
                                               unsigned short* __restrict__ v_bf,
                                               const float* __restrict__ query,
                                               const unsigned short* __restrict__ Bhi,
                                               const unsigned short* __restrict__ Blo,
                                               const float* __restrict__ boff,
                                               const float* __restrict__ baw,
                                               float* __restrict__ offP) {
  __shared__ __align__(16) unsigned char smem[32768];
  int bid = blockIdx.x;
  if (bid < 512) {
    int bx, by; swz512(bid, bx, by);
    gemm_body64_f32A(smem, value, Wv_t, b_v, v_bf, bx, by);
  } else {
    offaw_body(smem, query, Bhi, Blo, boff, baw, offP, bid - 512);
  }
}

// ---------------- K3: out = attn @ W_out + b_out (512 blocks, swizzled) -----------
__global__ __launch_bounds__(256) void gemm2_k(const unsigned short* __restrict__ A,
                                               const unsigned short* __restrict__ Bt,
                                               const float* __restrict__ bias,
                                               float* __restrict__ C) {
  __shared__ __align__(16) unsigned char smem[32768];
  int bx, by; swz512(blockIdx.x, bx, by);
  gemm_body64_bf16A(smem, A, Bt, bias, C, bx, by);
}

// ---------------- K2: fused softmax + 1-D grid-sample gather ----------------------
// XCD chunk swizzle (T1): 2048 blocks, 256 per batch; map XCD i -> batch i so each
// XCD's L2 holds one 2 MB v-slice instead of all 16 MB.  2048 % 8 == 0 -> bijective.
__global__ __launch_bounds__(256) void sample_kernel(const float* __restrict__ P,
                                                     const unsigned short* __restrict__ v,
                                                     unsigned short* __restrict__ attn) {
  int bid = ((blockIdx.x & 7) << 8) + (blockIdx.x >> 3);   // xcd*256 + idx
  int tid = threadIdx.x;
  int rr = tid >> 5, hp = tid & 31;
  int row = bid * 8 + rr;
  int l = row & 2047;
  __shared__ float s_w0[8][32], s_w1[8][32];
  __shared__ int s_i0[8][32], s_i1[8][32];
  {
    int base = row * 96;
    float lg = P[base + 64 + hp] + P[PSZF + base + 64 + hp];
    float mx = fmaxf(lg, __shfl_xor(lg, 1));
    mx = fmaxf(mx, __shfl_xor(mx, 2));
    float e = __expf(lg - mx);
    float s = e + __shfl_xor(e, 1);
    s = s + __shfl_xor(s, 2);
    float aw = e / s;

    float ox = P[base + 2 * hp] + P[PSZF + base + 2 * hp];
    float oy = P[base + 2 * hp + 1] + P[PSZF + base + 2 * hp + 1];
    float refy = (float)l * (1.0f / 2047.0f);
    float lx = fminf(fmaxf(ox, 0.0f), 1.0f);
    float ly = fminf(fmaxf(oy + refy, 0.0f), 1.0f);
    float ix = ((lx + 1.0f) * 2048.0f - 1.0f) * 0.5f;
    float ywt = 1.0f - ly * 0.5f;
    float ix0 = floorf(ix);
    float fx = ix - ix0;
    int i0 = (int)ix0;
    int i1 = i0 + 1;
    s_w0[rr][hp] = aw * ywt * (1.0f - fx);
    s_w1[rr][hp] = (i1 < 2048) ? (aw * ywt * fx) : 0.0f;
    s_i0[rr][hp] = i0;
    s_i1[rr][hp] = (i1 < 2048) ? i1 : 2047;
  }
  __syncthreads();

  int b = (bid * 8) >> 11;                 // 8 rows never cross a batch
  int h = tid >> 5, c = (tid & 31) << 1;
  const unsigned short* vhc = v + ((size_t)(b << 11)) * 512 + h * 64 + c;
#pragma unroll
  for (int r8 = 0; r8 < 8; r8++) {
    int row2 = bid * 8 + r8;
    float ax = 0.0f, ay = 0.0f;
#pragma unroll
    for (int p = 0; p < 4; p++) {
      int t = (h << 2) + p;
      unsigned g0 = *(const unsigned*)(vhc + ((size_t)s_i0[r8][t] << 9));
      unsigned g1 = *(const unsigned*)(vhc + ((size_t)s_i1[r8][t] << 9));
      float w0 = s_w0[r8][t], w1 = s_w1[r8][t];
      ax += w0 * bf2f((unsigned short)g0) + w1 * bf2f((unsigned short)g1);
      ay += w0 * bf2f((unsigned short)(g0 >> 16)) + w1 * bf2f((unsigned short)(g1 >> 16));
    }
    unsigned packed = (unsigned)f2bf(ax) | ((unsigned)f2bf(ay) << 16);
    *(unsigned*)(attn + (size_t)row2 * 512 + h * 64 + c) = packed;
  }
}

// ---------------- host launcher ----------------
extern "C" void kernel_launch(void* const* d_in, const int* in_sizes, int n_in,
                              void* d_out, int out_size, void* d_ws, size_t ws_size,
                              hipStream_t stream) {
  (void)in_sizes; (void)n_in; (void)out_size; (void)ws_size;
  const float* query = (const float*)d_in[0];
  // d_in[1] = key_in : unused by the reference
  const float* value = (const float*)d_in[2];
  const float* W_v   = (const float*)d_in[3];
  const float* b_v   = (const float*)d_in[4];
  const float* W_off = (const float*)d_in[5];
  const float* b_off = (const float*)d_in[6];
  const float* W_aw  = (const float*)d_in[7];
  const float* b_aw  = (const float*)d_in[8];
  const float* W_out = (const float*)d_in[9];
  const float* b_out = (const float*)d_in[10];
  float* out = (float*)d_out;

  char* ws = (char*)d_ws;
  const size_t MB = 1ull << 20;
  unsigned short* attn   = (unsigned short*)(ws);                  // 16 MB (attn bf16)
  unsigned short* v_bf   = (unsigned short*)(ws + 16 * MB);        // 16 MB (v projection)
  float* offP            = (float*)(ws + 32 * MB);                 // 2 x 6 MB offaw partials
  unsigned short* Wv_t   = (unsigned short*)(ws + 48 * MB);        // 0.5 MB
  unsigned short* Wo_t   = (unsigned short*)(ws + 48 * MB + 524288);
  unsigned short* Bhi    = (unsigned short*)(ws + 49 * MB);        // 96 KB
  unsigned short* Blo    = (unsigned short*)(ws + 49 * MB + 98304);

  // K0: weight prep only (573,440 threads = 2240 blocks)
  prep_all<<<2240, 256, 0, stream>>>(W_v, W_out, W_off, W_aw, Wv_t, Wo_t, Bhi, Blo);
  // K1: v = value@W_v + b_v (fp32 A prefetched, bf16 out)  ||  offaw split-bf16
  mega_k1<<<1024, 256, 0, stream>>>(value, Wv_t, b_v, v_bf, query, Bhi, Blo,
                                    b_off, b_aw, offP);
  // K2: softmax + grid-sample gather -> attn (bf16), XCD-swizzled
  sample_kernel<<<2048, 256, 0, stream>>>(offP, v_bf, attn);
  // K3: out = attn @ W_out + b_out (fp32 out)
  gemm2_k<<<512, 256, 0, stream>>>(attn, Wo_t, b_out, out);
}